// Round 2
// baseline (598.873 us; speedup 1.0000x reference)
//
#include <hip/hip_runtime.h>
#include <math.h>

#define N_ATOMS 100000
#define N_EDGES 1600000
#define NSTRUCT 64

__device__ __forceinline__ float frcp(float x) { return __builtin_amdgcn_rcpf(x); }
__device__ __forceinline__ float silu(float v) { return v * frcp(1.f + __expf(-v)); }

// ---------------- CSR build ----------------

__global__ void k_hist(const int* __restrict__ i_idx, int* __restrict__ counts) {
    int e = blockIdx.x * 256 + threadIdx.x;
    if (e < N_EDGES) atomicAdd(&counts[i_idx[e]], 1);
}

__global__ void k_blocksum(const int* __restrict__ counts, int* __restrict__ bsum) {
    __shared__ int sd[256];
    int a = blockIdx.x * 256 + threadIdx.x;
    sd[threadIdx.x] = (a < N_ATOMS) ? counts[a] : 0;
    __syncthreads();
    for (int off = 128; off > 0; off >>= 1) {
        if (threadIdx.x < off) sd[threadIdx.x] += sd[threadIdx.x + off];
        __syncthreads();
    }
    if (threadIdx.x == 0) bsum[blockIdx.x] = sd[0];
}

__global__ void k_scanb(const int* __restrict__ bsum, int* __restrict__ bpre, int nb) {
    __shared__ int sd[512];
    int t = threadIdx.x;
    int v0 = (t < nb) ? bsum[t] : 0;
    sd[t] = v0;
    __syncthreads();
    for (int off = 1; off < 512; off <<= 1) {
        int v = (t >= off) ? sd[t - off] : 0;
        __syncthreads();
        sd[t] += v;
        __syncthreads();
    }
    if (t < nb) bpre[t] = sd[t] - v0;
}

__global__ void k_rowstart(const int* __restrict__ counts, const int* __restrict__ bpre,
                           int* __restrict__ row_start, int* __restrict__ cursor) {
    __shared__ int sd[256];
    int t = threadIdx.x;
    int a = blockIdx.x * 256 + t;
    int v = (a < N_ATOMS) ? counts[a] : 0;
    sd[t] = v;
    __syncthreads();
    for (int off = 1; off < 256; off <<= 1) {
        int add = (t >= off) ? sd[t - off] : 0;
        __syncthreads();
        sd[t] += add;
        __syncthreads();
    }
    if (a < N_ATOMS) {
        int excl = sd[t] - v + bpre[blockIdx.x];
        row_start[a] = excl;
        cursor[a] = excl;
    }
}

__global__ void k_scatter(const int* __restrict__ i_idx, const int* __restrict__ j_idx,
                          int* __restrict__ cursor, int* __restrict__ ej) {
    int e = blockIdx.x * 256 + threadIdx.x;
    if (e < N_EDGES) {
        int i = i_idx[e];
        int s = atomicAdd(&cursor[i], 1);
        ej[s] = j_idx[e];
    }
}

// ---------------- pack atom data: {mx,my,mz,px},{py,pz,mnorm,species} ----------------

__global__ void k_pack(const float* __restrict__ pos, const float* __restrict__ mmv,
                       const int* __restrict__ species, float* __restrict__ packed) {
    int a = blockIdx.x * 256 + threadIdx.x;
    if (a >= N_ATOMS) return;
    float mx = mmv[a * 3 + 0], my = mmv[a * 3 + 1], mz = mmv[a * 3 + 2];
    float px = pos[a * 3 + 0], py = pos[a * 3 + 1], pz = pos[a * 3 + 2];
    float mn = sqrtf(mx * mx + my * my + mz * mz + 1e-9f);
    float4* o = (float4*)packed;
    o[a * 2 + 0] = make_float4(mx, my, mz, px);
    o[a * 2 + 1] = make_float4(py, pz, mn, (float)species[a]);
}

// ---------------- edge accumulate: 8 lanes per atom, lane s owns seg row s ----------------

__global__ __launch_bounds__(256) void k_edgeacc(
    const float* __restrict__ packed, const float* __restrict__ cheb,
    const int* __restrict__ row_start, const int* __restrict__ counts,
    const int* __restrict__ ej, float* __restrict__ segbuf) {
    int tid = blockIdx.x * 256 + threadIdx.x;
    int a = tid >> 3;
    int s = tid & 7;
    if (a >= N_ATOMS) return;

    const float4* pk = (const float4*)packed;
    float4 i0 = pk[a * 2 + 0];
    float4 i1 = pk[a * 2 + 1];
    float mix = i0.x, miy = i0.y, miz = i0.z;
    float pix = i0.w, piy = i1.x, piz = i1.y;
    float mni = i1.z;
    int spi = (int)i1.w;
    float inv_mni = frcp(mni);
    float mhix = mix * inv_mni, mhiy = miy * inv_mni, mhiz = miz * inv_mni;

    float seg0 = 0.f, seg1 = 0.f, seg2 = 0.f, seg3 = 0.f;
    float seg4 = 0.f, seg5 = 0.f, seg6 = 0.f, seg7 = 0.f;
    float vcx = 0.f, vcy = 0.f, vcz = 0.f;

    int start = row_start[a], cnt = counts[a];
    const float* cbase = cheb + spi * 4 * 96 + s * 12;

    for (int it = 0; it < cnt; ++it) {
        int j = ej[start + it];
        float4 j0 = pk[j * 2 + 0];
        float4 j1 = pk[j * 2 + 1];
        float mjx = j0.x, mjy = j0.y, mjz = j0.z;
        float rx = j0.w - pix, ry = j1.x - piy, rz = j1.y - piz;
        float mnj = j1.z;
        int spj = (int)j1.w;

        float d = sqrtf(rx * rx + ry * ry + rz * rz + 1e-9f);
        float invd = frcp(d);
        float rhx = rx * invd, rhy = ry * invd, rhz = rz * invd;

        // Chebyshev in x = clamp(d/3-1)
        float x = d * (1.f / 3.f) - 1.f;
        x = fminf(fmaxf(x, -1.f), 1.f);
        float x2 = 2.f * x;
        float T0 = 1.f, T1 = x;
        float T2 = x2 * T1 - T0, T3 = x2 * T2 - T1, T4 = x2 * T3 - T2, T5 = x2 * T4 - T3;
        float T6 = x2 * T5 - T4, T7 = x2 * T6 - T5, T8 = x2 * T7 - T6, T9 = x2 * T8 - T7;
        float T10 = x2 * T9 - T8, T11 = x2 * T10 - T9;
        float fcut = (d < 6.f) ? 0.5f * (__cosf(d * 0.52359877559829887f) + 1.f) : 0.f;

        // this lane's phi[s]: 12-coeff dot (coalesced across the 8 lanes of the group)
        const float4* c4 = (const float4*)(cbase + spj * 96);
        float4 c0 = c4[0], c1 = c4[1], c2 = c4[2];
        float phis = c0.x * T0 + c0.y * T1 + c0.z * T2 + c0.w * T3;
        phis += c1.x * T4 + c1.y * T5 + c1.z * T6 + c1.w * T7;
        phis += c2.x * T8 + c2.y * T9 + c2.z * T10 + c2.w * T11;
        phis *= fcut;

        // share phi across the 8-lane group
        float p0 = __shfl(phis, 0, 8), p1 = __shfl(phis, 1, 8);
        float p2 = __shfl(phis, 2, 8), p3 = __shfl(phis, 3, 8);
        float p4 = __shfl(phis, 4, 8), p5 = __shfl(phis, 5, 8);
        float p6 = __shfl(phis, 6, 8), p7 = __shfl(phis, 7, 8);

        // all w values (cheap), select this lane's
        float invmnj = frcp(mnj);
        float mhjx = mjx * invmnj, mhjy = mjy * invmnj, mhjz = mjz * invmnj;
        float w1 = mix * mjx + miy * mjy + miz * mjz;
        float dhi = mhix * rhx + mhiy * rhy + mhiz * rhz;
        float dhj = mhjx * rhx + mhjy * rhy + mhjz * rhz;
        float w2 = dhi * dhi;
        float w3 = dhj * dhj;
        float cx = miy * mjz - miz * mjy;
        float cy = miz * mjx - mix * mjz;
        float cz = mix * mjy - miy * mjx;
        float w4 = rhx * cx + rhy * cy + rhz * cz;
        float w6 = (mhix * mhjx + mhiy * mhjy + mhiz * mhjz) * mnj;
        float w7 = mnj * mnj;
        float ws = 1.f;
        ws = (s == 1) ? w1 : ws;
        ws = (s == 2) ? w2 : ws;
        ws = (s == 3) ? w3 : ws;
        ws = (s == 4) ? w4 : ws;
        ws = (s == 5) ? mnj : ws;
        ws = (s == 6) ? w6 : ws;
        ws = (s == 7) ? w7 : ws;

        seg0 = fmaf(ws, p0, seg0); seg1 = fmaf(ws, p1, seg1);
        seg2 = fmaf(ws, p2, seg2); seg3 = fmaf(ws, p3, seg3);
        seg4 = fmaf(ws, p4, seg4); seg5 = fmaf(ws, p5, seg5);
        seg6 = fmaf(ws, p6, seg6); seg7 = fmaf(ws, p7, seg7);
        vcx = fmaf(phis, rhx, vcx);
        vcy = fmaf(phis, rhy, vcy);
        vcz = fmaf(phis, rhz, vcz);
    }

    float* o = segbuf + (size_t)a * 72;
    float4* o4 = (float4*)(o + s * 8);
    o4[0] = make_float4(seg0, seg1, seg2, seg3);
    o4[1] = make_float4(seg4, seg5, seg6, seg7);
    o[64 + s] = vcx * vcx + vcy * vcy + vcz * vcz;
}

// ---------------- structure MLP: 4 waves/block, wave w owns outputs [16w,16w+16) ----------------

__global__ __launch_bounds__(256) void k_struct(
    const float* __restrict__ segbuf, const int* __restrict__ species,
    const int* __restrict__ batch, const float* __restrict__ embt,
    const float* __restrict__ shift,
    const float* __restrict__ Ws1, const float* __restrict__ bs1,
    const float* __restrict__ Ws2, const float* __restrict__ bs2,
    const float* __restrict__ Ws3, const float* __restrict__ bs3,
    float* __restrict__ out) {
    __shared__ float h1sh[64][65];
    __shared__ float epart[64];
    __shared__ float spart[NSTRUCT];
    int t = threadIdx.x;
    int w = t >> 6;
    int l = t & 63;
    if (t < 64) { epart[t] = 0.f; spart[t] = 0.f; }
    __syncthreads();

    int a = blockIdx.x * 64 + l;
    bool valid = a < N_ATOMS;

    float x[32];
    if (valid) {
        const float4* sb4 = (const float4*)(segbuf + (size_t)a * 72);
        float4 v0 = sb4[0], v1 = sb4[1];    // A row
        float4 v2 = sb4[16], v3 = sb4[17];  // |vec|^2
        x[0] = v0.x; x[1] = v0.y; x[2] = v0.z; x[3] = v0.w;
        x[4] = v1.x; x[5] = v1.y; x[6] = v1.z; x[7] = v1.w;
        x[8] = v2.x; x[9] = v2.y; x[10] = v2.z; x[11] = v2.w;
        x[12] = v3.x; x[13] = v3.y; x[14] = v3.z; x[15] = v3.w;
        int spi = species[a];
        const float4* e4 = (const float4*)(embt + spi * 16);
        float4 e0 = e4[0], e1 = e4[1], e2 = e4[2], e3 = e4[3];
        x[16] = e0.x; x[17] = e0.y; x[18] = e0.z; x[19] = e0.w;
        x[20] = e1.x; x[21] = e1.y; x[22] = e1.z; x[23] = e1.w;
        x[24] = e2.x; x[25] = e2.y; x[26] = e2.z; x[27] = e2.w;
        x[28] = e3.x; x[29] = e3.y; x[30] = e3.z; x[31] = e3.w;
    } else {
#pragma unroll
        for (int k = 0; k < 32; k++) x[k] = 0.f;
    }

    int ob = w * 16;
    float h1p[16];
#pragma unroll
    for (int oo = 0; oo < 16; oo++) h1p[oo] = bs1[ob + oo];
#pragma unroll
    for (int k = 0; k < 32; k++) {
        float xv = x[k];
#pragma unroll
        for (int oo = 0; oo < 16; oo++) h1p[oo] = fmaf(xv, Ws1[k * 64 + ob + oo], h1p[oo]);
    }
#pragma unroll
    for (int oo = 0; oo < 16; oo++) h1sh[l][ob + oo] = silu(h1p[oo]);
    __syncthreads();

    float h2p[16];
#pragma unroll
    for (int oo = 0; oo < 16; oo++) h2p[oo] = bs2[ob + oo];
#pragma unroll 8
    for (int k = 0; k < 64; k++) {
        float hv = h1sh[l][k];
#pragma unroll
        for (int oo = 0; oo < 16; oo++) h2p[oo] = fmaf(hv, Ws2[k * 64 + ob + oo], h2p[oo]);
    }
    float ep = 0.f;
#pragma unroll
    for (int oo = 0; oo < 16; oo++) ep = fmaf(silu(h2p[oo]), Ws3[ob + oo], ep);
    if (valid) atomicAdd(&epart[l], ep);
    __syncthreads();

    if (t < 64) {
        int aa = blockIdx.x * 64 + t;
        if (aa < N_ATOMS) {
            float e = epart[t] + bs3[0] + shift[species[aa]];
            atomicAdd(&spart[batch[aa]], e);
        }
    }
    __syncthreads();
    if (t < NSTRUCT) {
        float v = spart[t];
        if (v != 0.f) atomicAdd(&out[t], v);
    }
}

// ---------------- magnetic MLP: 9 waves/block, wave h owns head h for 64 atoms ----------------

__global__ __launch_bounds__(576) void k_mag(
    const float* __restrict__ segbuf, const float* __restrict__ packed,
    const int* __restrict__ species, const int* __restrict__ batch,
    const float* __restrict__ embt,
    const float* __restrict__ Wm1, const float* __restrict__ bm1,
    const float* __restrict__ Wm2, const float* __restrict__ bm2,
    const float* __restrict__ Wm3, const float* __restrict__ bm3,
    float* __restrict__ out) {
    __shared__ float spart[NSTRUCT];
    int t = threadIdx.x;
    int h = t >> 6;   // 0..8, wave-uniform
    int l = t & 63;
    if (t < NSTRUCT) spart[t] = 0.f;
    __syncthreads();

    int a = blockIdx.x * 64 + l;
    if (a < N_ATOMS) {
        int kk = (h <= 5) ? h : (h - 1);
        const float4* sb4 = (const float4*)(segbuf + (size_t)a * 72 + kk * 8);
        float4 s0 = sb4[0], s1 = sb4[1];
        float amp = (h == 0 || h == 5) ? packed[a * 8 + 6] : 1.f;
        float xm[8];
        xm[0] = s0.x * amp; xm[1] = s0.y * amp; xm[2] = s0.z * amp; xm[3] = s0.w * amp;
        xm[4] = s1.x * amp; xm[5] = s1.y * amp; xm[6] = s1.z * amp; xm[7] = s1.w * amp;

        int spi = species[a];
        const float4* e4 = (const float4*)(embt + spi * 16);
        float4 e0 = e4[0], e1 = e4[1], e2 = e4[2], e3 = e4[3];
        float emb[16] = {e0.x, e0.y, e0.z, e0.w, e1.x, e1.y, e1.z, e1.w,
                         e2.x, e2.y, e2.z, e2.w, e3.x, e3.y, e3.z, e3.w};

        float hm1[32];
#pragma unroll
        for (int o = 0; o < 32; o++) hm1[o] = bm1[h * 32 + o];
#pragma unroll
        for (int d = 0; d < 8; d++) {
            float xv = xm[d];
#pragma unroll
            for (int o = 0; o < 32; o++) hm1[o] = fmaf(xv, Wm1[(h * 24 + d) * 32 + o], hm1[o]);
        }
#pragma unroll
        for (int d = 0; d < 16; d++) {
            float xv = emb[d];
#pragma unroll
            for (int o = 0; o < 32; o++) hm1[o] = fmaf(xv, Wm1[(h * 24 + 8 + d) * 32 + o], hm1[o]);
        }
#pragma unroll
        for (int o = 0; o < 32; o++) hm1[o] = silu(hm1[o]);

        float e_head = bm3[h];
        for (int o = 0; o < 32; o++) {
            float acc = bm2[h * 32 + o];
#pragma unroll
            for (int d = 0; d < 32; d++) acc = fmaf(hm1[d], Wm2[(h * 32 + d) * 32 + o], acc);
            e_head = fmaf(silu(acc), Wm3[h * 32 + o], e_head);
        }
        atomicAdd(&spart[batch[a]], e_head);
    }
    __syncthreads();
    if (t < NSTRUCT) {
        float v = spart[t];
        if (v != 0.f) atomicAdd(&out[t], v);
    }
}

// ---------------- launch ----------------

extern "C" void kernel_launch(void* const* d_in, const int* in_sizes, int n_in,
                              void* d_out, int out_size, void* d_ws, size_t ws_size,
                              hipStream_t stream) {
    const float* pos   = (const float*)d_in[0];
    const float* mmv   = (const float*)d_in[1];
    const int* species = (const int*)d_in[2];
    const int* i_idx   = (const int*)d_in[3];
    const int* j_idx   = (const int*)d_in[4];
    const int* batch   = (const int*)d_in[5];
    const float* cheb  = (const float*)d_in[6];
    const float* embt  = (const float*)d_in[7];
    const float* shift = (const float*)d_in[8];
    const float* Ws1 = (const float*)d_in[9];
    const float* bs1 = (const float*)d_in[10];
    const float* Ws2 = (const float*)d_in[11];
    const float* bs2 = (const float*)d_in[12];
    const float* Ws3 = (const float*)d_in[13];
    const float* bs3 = (const float*)d_in[14];
    const float* Wm1 = (const float*)d_in[15];
    const float* bm1 = (const float*)d_in[16];
    const float* Wm2 = (const float*)d_in[17];
    const float* bm2 = (const float*)d_in[18];
    const float* Wm3 = (const float*)d_in[19];
    const float* bm3 = (const float*)d_in[20];
    float* out = (float*)d_out;

    char* ws = (char*)d_ws;
    int* counts    = (int*)(ws + 0);         // 400 KB
    int* row_start = (int*)(ws + 400384);
    int* cursor    = (int*)(ws + 800768);
    int* bsum      = (int*)(ws + 1201152);
    int* bpre      = (int*)(ws + 1202816);
    int* ej        = (int*)(ws + 1204480);   // 6.4 MB
    float* packed  = (float*)(ws + 7604480); // 3.2 MB
    float* segbuf  = (float*)(ws + 10804480); // 28.8 MB (end ~39.6 MB)

    const int NB_ATOM = (N_ATOMS + 255) / 256;   // 391
    const int NB_EDGE = (N_EDGES + 255) / 256;   // 6250
    const int NB_A64  = (N_ATOMS + 63) / 64;     // 1563

    hipMemsetAsync(counts, 0, N_ATOMS * sizeof(int), stream);
    hipMemsetAsync(out, 0, NSTRUCT * sizeof(float), stream);

    k_pack<<<NB_ATOM, 256, 0, stream>>>(pos, mmv, species, packed);
    k_hist<<<NB_EDGE, 256, 0, stream>>>(i_idx, counts);
    k_blocksum<<<NB_ATOM, 256, 0, stream>>>(counts, bsum);
    k_scanb<<<1, 512, 0, stream>>>(bsum, bpre, NB_ATOM);
    k_rowstart<<<NB_ATOM, 256, 0, stream>>>(counts, bpre, row_start, cursor);
    k_scatter<<<NB_EDGE, 256, 0, stream>>>(i_idx, j_idx, cursor, ej);
    k_edgeacc<<<(N_ATOMS * 8 + 255) / 256, 256, 0, stream>>>(packed, cheb, row_start, counts, ej, segbuf);
    k_struct<<<NB_A64, 256, 0, stream>>>(segbuf, species, batch, embt, shift,
                                         Ws1, bs1, Ws2, bs2, Ws3, bs3, out);
    k_mag<<<NB_A64, 576, 0, stream>>>(segbuf, packed, species, batch, embt,
                                      Wm1, bm1, Wm2, bm2, Wm3, bm3, out);
}

// Round 3
// 373.934 us; speedup vs baseline: 1.6015x; 1.6015x over previous
//
#include <hip/hip_runtime.h>
#include <math.h>

#define N_ATOMS 100000
#define N_EDGES 1600000
#define NSTRUCT 64

__device__ __forceinline__ float frcp(float x) { return __builtin_amdgcn_rcpf(x); }
__device__ __forceinline__ float silu(float v) { return v * frcp(1.f + __expf(-v)); }

__device__ __forceinline__ unsigned pack2(float a, float b) {
    unsigned ua = __float_as_uint(a), ub = __float_as_uint(b);
    ua = (ua + 0x7fffu + ((ua >> 16) & 1u)) >> 16;
    ub = (ub + 0x7fffu + ((ub >> 16) & 1u)) >> 16;
    return ua | (ub << 16);
}
__device__ __forceinline__ float lo16(unsigned u) { return __uint_as_float(u << 16); }
__device__ __forceinline__ float hi16(unsigned u) { return __uint_as_float(u & 0xffff0000u); }

// ---------------- CSR build ----------------

__global__ void k_hist(const int* __restrict__ i_idx, int* __restrict__ counts) {
    int e = blockIdx.x * 256 + threadIdx.x;
    if (e < N_EDGES) atomicAdd(&counts[i_idx[e]], 1);
}

__global__ void k_blocksum(const int* __restrict__ counts, int* __restrict__ bsum) {
    __shared__ int sd[256];
    int a = blockIdx.x * 256 + threadIdx.x;
    sd[threadIdx.x] = (a < N_ATOMS) ? counts[a] : 0;
    __syncthreads();
    for (int off = 128; off > 0; off >>= 1) {
        if (threadIdx.x < off) sd[threadIdx.x] += sd[threadIdx.x + off];
        __syncthreads();
    }
    if (threadIdx.x == 0) bsum[blockIdx.x] = sd[0];
}

__global__ void k_scanb(const int* __restrict__ bsum, int* __restrict__ bpre, int nb) {
    __shared__ int sd[512];
    int t = threadIdx.x;
    int v0 = (t < nb) ? bsum[t] : 0;
    sd[t] = v0;
    __syncthreads();
    for (int off = 1; off < 512; off <<= 1) {
        int v = (t >= off) ? sd[t - off] : 0;
        __syncthreads();
        sd[t] += v;
        __syncthreads();
    }
    if (t < nb) bpre[t] = sd[t] - v0;
}

__global__ void k_rowstart(const int* __restrict__ counts, const int* __restrict__ bpre,
                           int* __restrict__ row_start, int* __restrict__ cursor) {
    __shared__ int sd[256];
    int t = threadIdx.x;
    int a = blockIdx.x * 256 + t;
    int v = (a < N_ATOMS) ? counts[a] : 0;
    sd[t] = v;
    __syncthreads();
    for (int off = 1; off < 256; off <<= 1) {
        int add = (t >= off) ? sd[t - off] : 0;
        __syncthreads();
        sd[t] += add;
        __syncthreads();
    }
    if (a < N_ATOMS) {
        int excl = sd[t] - v + bpre[blockIdx.x];
        row_start[a] = excl;
        cursor[a] = excl;
    }
}

// ---------------- pack atom data: {mx,my,mz,px},{py,pz,mnorm,species} ----------------

__global__ void k_pack(const float* __restrict__ pos, const float* __restrict__ mmv,
                       const int* __restrict__ species, float* __restrict__ packed) {
    int a = blockIdx.x * 256 + threadIdx.x;
    if (a >= N_ATOMS) return;
    float mx = mmv[a * 3 + 0], my = mmv[a * 3 + 1], mz = mmv[a * 3 + 2];
    float px = pos[a * 3 + 0], py = pos[a * 3 + 1], pz = pos[a * 3 + 2];
    float mn = sqrtf(mx * mx + my * my + mz * mz + 1e-9f);
    float4* o = (float4*)packed;
    o[a * 2 + 0] = make_float4(mx, my, mz, px);
    o[a * 2 + 1] = make_float4(py, pz, mn, (float)species[a]);
}

// ---------------- phase A: per-edge compute, write 48B bf16 record at CSR slot ----------------

__global__ __launch_bounds__(256) void k_edges(
    const float* __restrict__ packed, const float* __restrict__ cheb,
    const int* __restrict__ i_idx, const int* __restrict__ j_idx,
    int* __restrict__ cursor, unsigned* __restrict__ recbuf) {
    int e = blockIdx.x * 256 + threadIdx.x;
    if (e >= N_EDGES) return;
    int i = i_idx[e], j = j_idx[e];
    const float4* pk = (const float4*)packed;
    float4 i0 = pk[i * 2 + 0], i1 = pk[i * 2 + 1];
    float4 j0 = pk[j * 2 + 0], j1 = pk[j * 2 + 1];

    float mix = i0.x, miy = i0.y, miz = i0.z;
    float mjx = j0.x, mjy = j0.y, mjz = j0.z;
    float rx = j0.w - i0.w, ry = j1.x - i1.x, rz = j1.y - i1.y;
    float mni = i1.z, mnj = j1.z;
    int spi = (int)i1.w, spj = (int)j1.w;

    float d = sqrtf(rx * rx + ry * ry + rz * rz + 1e-9f);
    float invd = frcp(d);
    float rhx = rx * invd, rhy = ry * invd, rhz = rz * invd;

    float x = d * (1.f / 3.f) - 1.f;
    x = fminf(fmaxf(x, -1.f), 1.f);
    float x2 = 2.f * x;
    float T[12];
    T[0] = 1.f; T[1] = x;
#pragma unroll
    for (int k = 2; k < 12; k++) T[k] = x2 * T[k - 1] - T[k - 2];
    float fcut = (d < 6.f) ? 0.5f * (__cosf(d * 0.52359877559829887f) + 1.f) : 0.f;

    const float* crow = cheb + (spi * 4 + spj) * 96;
    float phi[8];
#pragma unroll
    for (int n = 0; n < 8; n++) {
        const float4* c4 = (const float4*)(crow + n * 12);
        float4 c0 = c4[0], c1 = c4[1], c2 = c4[2];
        float acc = c0.x * T[0] + c0.y * T[1] + c0.z * T[2] + c0.w * T[3];
        acc += c1.x * T[4] + c1.y * T[5] + c1.z * T[6] + c1.w * T[7];
        acc += c2.x * T[8] + c2.y * T[9] + c2.z * T[10] + c2.w * T[11];
        phi[n] = acc * fcut;
    }

    float inv_mni = frcp(mni), inv_mnj = frcp(mnj);
    float mhix = mix * inv_mni, mhiy = miy * inv_mni, mhiz = miz * inv_mni;
    float mhjx = mjx * inv_mnj, mhjy = mjy * inv_mnj, mhjz = mjz * inv_mnj;
    float w1 = mix * mjx + miy * mjy + miz * mjz;
    float dhi = mhix * rhx + mhiy * rhy + mhiz * rhz;
    float dhj = mhjx * rhx + mhjy * rhy + mhjz * rhz;
    float w2 = dhi * dhi, w3 = dhj * dhj;
    float cx = miy * mjz - miz * mjy;
    float cy = miz * mjx - mix * mjz;
    float cz = mix * mjy - miy * mjx;
    float w4 = rhx * cx + rhy * cy + rhz * cz;
    float w6 = (mhix * mhjx + mhiy * mhjy + mhiz * mhjz) * mnj;
    float w7 = mnj * mnj;

    int slot = atomicAdd(&cursor[i], 1);
    uint4* rp = (uint4*)recbuf + (size_t)slot * 3;
    rp[0] = make_uint4(pack2(phi[0], phi[1]), pack2(phi[2], phi[3]),
                       pack2(phi[4], phi[5]), pack2(phi[6], phi[7]));
    rp[1] = make_uint4(pack2(w1, w2), pack2(w3, w4), pack2(mnj, w6), pack2(w7, rhx));
    rp[2] = make_uint4(pack2(rhy, rhz), 0u, 0u, 0u);
}

// ---------------- phase B: 8 lanes/atom, lane s owns phi-column s ----------------

__global__ __launch_bounds__(256) void k_reduce(
    const unsigned* __restrict__ recbuf, const int* __restrict__ row_start,
    const int* __restrict__ counts, float* __restrict__ segbuf) {
    int tid = blockIdx.x * 256 + threadIdx.x;
    int a = tid >> 3;
    int s = tid & 7;
    if (a >= N_ATOMS) return;

    int start = row_start[a], cnt = counts[a];
    const uint4* rp4 = (const uint4*)recbuf;
    const uint2* rp2 = (const uint2*)recbuf;

    // seg[k][s] accumulators: k = w-row index, column s fixed per lane
    float sg0 = 0.f, sg1 = 0.f, sg2 = 0.f, sg3 = 0.f;
    float sg4 = 0.f, sg5 = 0.f, sg6 = 0.f, sg7 = 0.f;
    float vcx = 0.f, vcy = 0.f, vcz = 0.f;

    for (int it = 0; it < cnt; ++it) {
        int base = (start + it) * 3;
        uint4 r0 = rp4[base], r1 = rp4[base + 1];
        uint2 r2 = rp2[base * 2 + 4];

        float phi0 = lo16(r0.x), phi1 = hi16(r0.x);
        float phi2 = lo16(r0.y), phi3 = hi16(r0.y);
        float phi4 = lo16(r0.z), phi5 = hi16(r0.z);
        float phi6 = lo16(r0.w), phi7 = hi16(r0.w);
        float w1 = lo16(r1.x), w2 = hi16(r1.x);
        float w3 = lo16(r1.y), w4 = hi16(r1.y);
        float w5 = lo16(r1.z), w6 = hi16(r1.z);
        float w7 = lo16(r1.w), rhx = hi16(r1.w);
        float rhy = lo16(r2.x), rhz = hi16(r2.x);

        float phis = phi0;
        phis = (s == 1) ? phi1 : phis;
        phis = (s == 2) ? phi2 : phis;
        phis = (s == 3) ? phi3 : phis;
        phis = (s == 4) ? phi4 : phis;
        phis = (s == 5) ? phi5 : phis;
        phis = (s == 6) ? phi6 : phis;
        phis = (s == 7) ? phi7 : phis;

        sg0 += phis;
        sg1 = fmaf(w1, phis, sg1);
        sg2 = fmaf(w2, phis, sg2);
        sg3 = fmaf(w3, phis, sg3);
        sg4 = fmaf(w4, phis, sg4);
        sg5 = fmaf(w5, phis, sg5);
        sg6 = fmaf(w6, phis, sg6);
        sg7 = fmaf(w7, phis, sg7);
        vcx = fmaf(phis, rhx, vcx);
        vcy = fmaf(phis, rhy, vcy);
        vcz = fmaf(phis, rhz, vcz);
    }

    float* o = segbuf + (size_t)a * 72;
    o[0 * 8 + s] = sg0; o[1 * 8 + s] = sg1; o[2 * 8 + s] = sg2; o[3 * 8 + s] = sg3;
    o[4 * 8 + s] = sg4; o[5 * 8 + s] = sg5; o[6 * 8 + s] = sg6; o[7 * 8 + s] = sg7;
    o[64 + s] = vcx * vcx + vcy * vcy + vcz * vcz;
}

// ---------------- structure MLP: thread=atom, weights in LDS ----------------

__global__ __launch_bounds__(256) void k_struct(
    const float* __restrict__ segbuf, const int* __restrict__ species,
    const int* __restrict__ batch, const float* __restrict__ embt,
    const float* __restrict__ shift,
    const float* __restrict__ Ws1, const float* __restrict__ bs1,
    const float* __restrict__ Ws2, const float* __restrict__ bs2,
    const float* __restrict__ Ws3, const float* __restrict__ bs3,
    float* __restrict__ out) {
    __shared__ float w1[2048];
    __shared__ float w2[4096];
    __shared__ float w3[64];
    __shared__ float b1[64];
    __shared__ float b2[64];
    __shared__ float spart[NSTRUCT];
    int t = threadIdx.x;
    for (int idx = t; idx < 2048; idx += 256) w1[idx] = Ws1[idx];
    for (int idx = t; idx < 4096; idx += 256) w2[idx] = Ws2[idx];
    if (t < 64) { w3[t] = Ws3[t]; b1[t] = bs1[t]; b2[t] = bs2[t]; spart[t] = 0.f; }
    __syncthreads();

    int a = blockIdx.x * 256 + t;
    if (a < N_ATOMS) {
        const float4* sb4 = (const float4*)(segbuf + (size_t)a * 72);
        float4 v0 = sb4[0], v1 = sb4[1];    // A row
        float4 v2 = sb4[16], v3 = sb4[17];  // |vec|^2
        int spi = species[a];
        const float4* e4 = (const float4*)(embt + spi * 16);
        float4 e0 = e4[0], e1 = e4[1], e2 = e4[2], e3 = e4[3];
        float x[32] = {v0.x, v0.y, v0.z, v0.w, v1.x, v1.y, v1.z, v1.w,
                       v2.x, v2.y, v2.z, v2.w, v3.x, v3.y, v3.z, v3.w,
                       e0.x, e0.y, e0.z, e0.w, e1.x, e1.y, e1.z, e1.w,
                       e2.x, e2.y, e2.z, e2.w, e3.x, e3.y, e3.z, e3.w};

        float h1[64];
#pragma unroll
        for (int o = 0; o < 64; o++) h1[o] = b1[o];
#pragma unroll
        for (int k = 0; k < 32; k++) {
            float xv = x[k];
            const float4* wr = (const float4*)&w1[k * 64];
#pragma unroll
            for (int q = 0; q < 16; q++) {
                float4 wv = wr[q];
                h1[q * 4 + 0] = fmaf(xv, wv.x, h1[q * 4 + 0]);
                h1[q * 4 + 1] = fmaf(xv, wv.y, h1[q * 4 + 1]);
                h1[q * 4 + 2] = fmaf(xv, wv.z, h1[q * 4 + 2]);
                h1[q * 4 + 3] = fmaf(xv, wv.w, h1[q * 4 + 3]);
            }
        }
#pragma unroll
        for (int o = 0; o < 64; o++) h1[o] = silu(h1[o]);

        float h2[64];
#pragma unroll
        for (int o = 0; o < 64; o++) h2[o] = b2[o];
#pragma unroll
        for (int k = 0; k < 64; k++) {
            float xv = h1[k];
            const float4* wr = (const float4*)&w2[k * 64];
#pragma unroll
            for (int q = 0; q < 16; q++) {
                float4 wv = wr[q];
                h2[q * 4 + 0] = fmaf(xv, wv.x, h2[q * 4 + 0]);
                h2[q * 4 + 1] = fmaf(xv, wv.y, h2[q * 4 + 1]);
                h2[q * 4 + 2] = fmaf(xv, wv.z, h2[q * 4 + 2]);
                h2[q * 4 + 3] = fmaf(xv, wv.w, h2[q * 4 + 3]);
            }
        }
        float e_struct = bs3[0] + shift[spi];
#pragma unroll
        for (int o = 0; o < 64; o++) e_struct = fmaf(silu(h2[o]), w3[o], e_struct);
        atomicAdd(&spart[batch[a]], e_struct);
    }
    __syncthreads();
    if (t < NSTRUCT) {
        float v = spart[t];
        if (v != 0.f) atomicAdd(&out[t], v);
    }
}

// ---------------- magnetic MLP: wave=head, Wm1+Wm2 staged in LDS ----------------

__global__ __launch_bounds__(576) void k_mag(
    const float* __restrict__ segbuf, const float* __restrict__ packed,
    const int* __restrict__ species, const int* __restrict__ batch,
    const float* __restrict__ embt,
    const float* __restrict__ Wm1, const float* __restrict__ bm1,
    const float* __restrict__ Wm2, const float* __restrict__ bm2,
    const float* __restrict__ Wm3, const float* __restrict__ bm3,
    float* __restrict__ out) {
    __shared__ float lw1[6912];   // 9 heads x 24 x 32
    __shared__ float lw2[9216];   // 9 heads x 32 x 32
    __shared__ float spart[NSTRUCT];
    int t = threadIdx.x;
    for (int idx = t; idx < 6912; idx += 576) lw1[idx] = Wm1[idx];
    for (int idx = t; idx < 9216; idx += 576) lw2[idx] = Wm2[idx];
    if (t < NSTRUCT) spart[t] = 0.f;
    __syncthreads();

    int h = __builtin_amdgcn_readfirstlane((int)(threadIdx.x >> 6));
    int l = t & 63;
    int a = blockIdx.x * 64 + l;
    if (a < N_ATOMS) {
        int kk = (h <= 5) ? h : (h - 1);
        const float4* sb4 = (const float4*)(segbuf + (size_t)a * 72 + kk * 8);
        float4 s0 = sb4[0], s1 = sb4[1];
        float amp = (h == 0 || h == 5) ? packed[a * 8 + 6] : 1.f;
        int spi = species[a];
        const float4* e4 = (const float4*)(embt + spi * 16);
        float4 e0 = e4[0], e1 = e4[1], e2 = e4[2], e3 = e4[3];
        float x[24] = {s0.x * amp, s0.y * amp, s0.z * amp, s0.w * amp,
                       s1.x * amp, s1.y * amp, s1.z * amp, s1.w * amp,
                       e0.x, e0.y, e0.z, e0.w, e1.x, e1.y, e1.z, e1.w,
                       e2.x, e2.y, e2.z, e2.w, e3.x, e3.y, e3.z, e3.w};

        const float* wb1 = lw1 + h * 768;
        float hm1[32];
#pragma unroll
        for (int o = 0; o < 32; o++) hm1[o] = bm1[h * 32 + o];
#pragma unroll
        for (int d = 0; d < 24; d++) {
            float xv = x[d];
            const float4* wr = (const float4*)&wb1[d * 32];
#pragma unroll
            for (int q = 0; q < 8; q++) {
                float4 wv = wr[q];
                hm1[q * 4 + 0] = fmaf(xv, wv.x, hm1[q * 4 + 0]);
                hm1[q * 4 + 1] = fmaf(xv, wv.y, hm1[q * 4 + 1]);
                hm1[q * 4 + 2] = fmaf(xv, wv.z, hm1[q * 4 + 2]);
                hm1[q * 4 + 3] = fmaf(xv, wv.w, hm1[q * 4 + 3]);
            }
        }
#pragma unroll
        for (int o = 0; o < 32; o++) hm1[o] = silu(hm1[o]);

        const float* wb2 = lw2 + h * 1024;
        float h2[32];
#pragma unroll
        for (int o = 0; o < 32; o++) h2[o] = bm2[h * 32 + o];
#pragma unroll
        for (int d = 0; d < 32; d++) {
            float xv = hm1[d];
            const float4* wr = (const float4*)&wb2[d * 32];
#pragma unroll
            for (int q = 0; q < 8; q++) {
                float4 wv = wr[q];
                h2[q * 4 + 0] = fmaf(xv, wv.x, h2[q * 4 + 0]);
                h2[q * 4 + 1] = fmaf(xv, wv.y, h2[q * 4 + 1]);
                h2[q * 4 + 2] = fmaf(xv, wv.z, h2[q * 4 + 2]);
                h2[q * 4 + 3] = fmaf(xv, wv.w, h2[q * 4 + 3]);
            }
        }
        float e_head = bm3[h];
#pragma unroll
        for (int o = 0; o < 32; o++) e_head = fmaf(silu(h2[o]), Wm3[h * 32 + o], e_head);
        atomicAdd(&spart[batch[a]], e_head);
    }
    __syncthreads();
    if (t < NSTRUCT) {
        float v = spart[t];
        if (v != 0.f) atomicAdd(&out[t], v);
    }
}

// ---------------- launch ----------------

extern "C" void kernel_launch(void* const* d_in, const int* in_sizes, int n_in,
                              void* d_out, int out_size, void* d_ws, size_t ws_size,
                              hipStream_t stream) {
    const float* pos   = (const float*)d_in[0];
    const float* mmv   = (const float*)d_in[1];
    const int* species = (const int*)d_in[2];
    const int* i_idx   = (const int*)d_in[3];
    const int* j_idx   = (const int*)d_in[4];
    const int* batch   = (const int*)d_in[5];
    const float* cheb  = (const float*)d_in[6];
    const float* embt  = (const float*)d_in[7];
    const float* shift = (const float*)d_in[8];
    const float* Ws1 = (const float*)d_in[9];
    const float* bs1 = (const float*)d_in[10];
    const float* Ws2 = (const float*)d_in[11];
    const float* bs2 = (const float*)d_in[12];
    const float* Ws3 = (const float*)d_in[13];
    const float* bs3 = (const float*)d_in[14];
    const float* Wm1 = (const float*)d_in[15];
    const float* bm1 = (const float*)d_in[16];
    const float* Wm2 = (const float*)d_in[17];
    const float* bm2 = (const float*)d_in[18];
    const float* Wm3 = (const float*)d_in[19];
    const float* bm3 = (const float*)d_in[20];
    float* out = (float*)d_out;

    char* ws = (char*)d_ws;
    int* counts        = (int*)(ws + 0);          // 400 KB
    int* row_start     = (int*)(ws + 400384);
    int* cursor        = (int*)(ws + 800768);
    int* bsum          = (int*)(ws + 1201152);
    int* bpre          = (int*)(ws + 1202816);
    float* packed      = (float*)(ws + 1204480);  // 3.2 MB
    float* segbuf      = (float*)(ws + 4404480);  // 28.8 MB
    unsigned* recbuf   = (unsigned*)(ws + 33204480); // 76.8 MB (end ~110 MB)

    const int NB_ATOM = (N_ATOMS + 255) / 256;   // 391
    const int NB_EDGE = (N_EDGES + 255) / 256;   // 6250
    const int NB_A64  = (N_ATOMS + 63) / 64;     // 1563

    hipMemsetAsync(counts, 0, N_ATOMS * sizeof(int), stream);
    hipMemsetAsync(out, 0, NSTRUCT * sizeof(float), stream);

    k_pack<<<NB_ATOM, 256, 0, stream>>>(pos, mmv, species, packed);
    k_hist<<<NB_EDGE, 256, 0, stream>>>(i_idx, counts);
    k_blocksum<<<NB_ATOM, 256, 0, stream>>>(counts, bsum);
    k_scanb<<<1, 512, 0, stream>>>(bsum, bpre, NB_ATOM);
    k_rowstart<<<NB_ATOM, 256, 0, stream>>>(counts, bpre, row_start, cursor);
    k_edges<<<NB_EDGE, 256, 0, stream>>>(packed, cheb, i_idx, j_idx, cursor, recbuf);
    k_reduce<<<(N_ATOMS * 8 + 255) / 256, 256, 0, stream>>>(recbuf, row_start, counts, segbuf);
    k_struct<<<NB_ATOM, 256, 0, stream>>>(segbuf, species, batch, embt, shift,
                                          Ws1, bs1, Ws2, bs2, Ws3, bs3, out);
    k_mag<<<NB_A64, 576, 0, stream>>>(segbuf, packed, species, batch, embt,
                                      Wm1, bm1, Wm2, bm2, Wm3, bm3, out);
}